// Round 3
// baseline (2499.510 us; speedup 1.0000x reference)
//
#include <hip/hip_runtime.h>
#include <math.h>

// Problem constants
#define Bb 64
#define Tt 1024
#define Dd 512
#define Hh 512

// ---------------------------------------------------------------------------
// Kernel 1: xw = x @ W[:D] + b   (M=65536, K=512, N=512), fp32.
// Unchanged (~470 us, 46% of fp32 vector peak). Writes into d_out; scan
// overwrites in place.
// ---------------------------------------------------------------------------
#define TM 128
#define TN 128
#define TK 16
#define LDP (TN + 4)

__global__ __launch_bounds__(256) void gemm_xw(const float* __restrict__ x,
                                               const float* __restrict__ W,
                                               const float* __restrict__ bias,
                                               float* __restrict__ out) {
    __shared__ float As[TK][LDP];
    __shared__ float Bs[TK][LDP];

    const int tid = threadIdx.x;
    const int m0 = blockIdx.x * TM;
    const int n0 = blockIdx.y * TN;
    const int tx = tid & 15;
    const int ty = tid >> 4;

    float acc[8][8];
    #pragma unroll
    for (int i = 0; i < 8; i++)
        #pragma unroll
        for (int j = 0; j < 8; j++) acc[i][j] = 0.0f;

    for (int k0 = 0; k0 < Dd; k0 += TK) {
        #pragma unroll
        for (int i = 0; i < 2; i++) {
            const int idx = tid * 2 + i;
            const int r = idx >> 2;
            const int c = idx & 3;
            const float4 av = *(const float4*)(x + (size_t)(m0 + r) * Dd + k0 + c * 4);
            As[c * 4 + 0][r] = av.x;
            As[c * 4 + 1][r] = av.y;
            As[c * 4 + 2][r] = av.z;
            As[c * 4 + 3][r] = av.w;
            const int kk = idx >> 5;
            const int cg = (idx & 31) * 4;
            const float4 bv = *(const float4*)(W + (size_t)(k0 + kk) * Hh + n0 + cg);
            *(float4*)(&Bs[kk][cg]) = bv;
        }
        __syncthreads();

        #pragma unroll
        for (int kk = 0; kk < TK; kk++) {
            float a[8], b[8];
            #pragma unroll
            for (int i = 0; i < 8; i++) a[i] = As[kk][ty * 8 + i];
            #pragma unroll
            for (int j = 0; j < 8; j++) b[j] = Bs[kk][tx * 8 + j];
            #pragma unroll
            for (int i = 0; i < 8; i++)
                #pragma unroll
                for (int j = 0; j < 8; j++) acc[i][j] += a[i] * b[j];
        }
        __syncthreads();
    }

    #pragma unroll
    for (int i = 0; i < 8; i++) {
        const size_t row = (size_t)(m0 + ty * 8 + i) * Hh;
        const int n = n0 + tx * 8;
        float4 v0, v1;
        v0.x = acc[i][0] + bias[n + 0];
        v0.y = acc[i][1] + bias[n + 1];
        v0.z = acc[i][2] + bias[n + 2];
        v0.w = acc[i][3] + bias[n + 3];
        v1.x = acc[i][4] + bias[n + 4];
        v1.y = acc[i][5] + bias[n + 5];
        v1.z = acc[i][6] + bias[n + 6];
        v1.w = acc[i][7] + bias[n + 7];
        *(float4*)(out + row + n) = v0;
        *(float4*)(out + row + n + 4) = v1;
    }
}

// ---------------------------------------------------------------------------
// Kernel 2: scan, ONE barrier per step, h fully register-resident.
//
// R3 post-mortem: self-tagged exchange works (7480 -> 1950 us) but the step
// period (4560 cy) is 2.4x the critical path. Cause: bar2 made EVERY wave
// wait for the pollers, and h round-tripped through LDS (hs) between the
// exchange and the FMA.
//
// New structure (per step, ONE __syncthreads):
//   B: FMA entirely from registers (hw[16] window + w4 weights) -> ps[t&1]
//   bar
//   C: tid<128: reduce ps[t&1] + xw -> tanh -> publish u64 (tag t+1) -> out
//   D: every 32-thread k-slice group pulls its OWN 16-value h_t window
//      straight from hbuf: lanes g<16 spin on self-tagged u64s (detection
//      and data in the same load), then 16 intra-wave __shfl broadcasts ->
//      hw[16] regs. No LDS hop, no second barrier: next FMA reads only regs.
//
// Hazard audit:
//   - ps WAR across steps: ps is parity double-buffered; B(t+2) (writes
//     ps[t&1]) happens after bar(t+1), which happens after every reducer's
//     C(t) read of ps[t&1]. Safe with the single barrier.
//   - hbuf slot reuse (parity-2): producer's tag t+3 store is data-dependent
//     on its D(t+1) loads (saw partners' t+2), which proves partners' D(t)
//     consumed its t+1. Same induction as R3, skew <= 1 step.
//   - Cross-replay: no reset needed; stale tail tags (1023/1024) never match
//     the strictly-increasing wants before being overwritten.
//   - Dead-man: poll bounded (2^14 iters ~ 4.5 ms); on trip, sdead gates all
//     later polls -> fast wrong-answer return instead of a dead container.
//
// Weights fp32 in regs (keep-alive pins them; R3 showed compiler uses AGPRs
// for them — 44 arch VGPR + 64 acc fits the 128/wave budget at 16 waves/CU,
// 1 block/CU, 256 blocks = capacity-exact co-residency).
// ---------------------------------------------------------------------------
__device__ unsigned long long g_hbuf[(size_t)Bb * 2 * Hh];   // 512 KB .bss

__global__ __launch_bounds__(1024, 4) void scan_rnn(const float* __restrict__ W,
                                                    float* __restrict__ out) {
    const float* __restrict__ Wh = W + (size_t)Dd * Hh;   // (H, H) row-major
    const int r = blockIdx.x & 63;        // batch row
    const int c = blockIdx.x >> 6;        // column group, 0..3 (cols 128c..)
    const int tid = threadIdx.x;
    const int g = tid & 31;               // 4-col group within slice
    const int s = tid >> 5;               // k-slice, 0..31 (k in [16s,16s+16))

    float* rowbase = out + (size_t)r * Tt * Hh;
    unsigned long long* hrow = g_hbuf + (size_t)r * 2 * Hh;  // [2][512] u64

    __shared__ float ps[2][32][128];      // parity-buffered partials, 32 KB
    __shared__ int sdead;                 // dead-man flag

    // ---- weight slice in registers: w4[kk] = Wh[16s+kk][128c+4g .. +3]
    float4 w4[16];
    {
        const float4* wbase = (const float4*)(Wh + (size_t)(s * 16) * Hh) + (c * 32 + g);
        #pragma unroll
        for (int kk = 0; kk < 16; kk++) w4[kk] = wbase[(size_t)kk * 128];
    }
    #pragma unroll
    for (int kk = 0; kk < 16; kk++)
        asm volatile("" : "+v"(w4[kk].x), "+v"(w4[kk].y), "+v"(w4[kk].z), "+v"(w4[kk].w));

    // h_{t-1} window for this thread's k-slice, in registers. h_{-1} = 0.
    float hw[16];
    #pragma unroll
    for (int i = 0; i < 16; i++) hw[i] = 0.0f;

    if (tid == 0) sdead = 0;
    __syncthreads();

    for (int t = 0; t < Tt; t++) {
        // xw prefetch for this step (in flight during FMA + barrier)
        float zpre = 0.0f;
        if (tid < 128) zpre = rowbase[(size_t)t * Hh + c * 128 + tid];

        // B: FMA — registers only (hw window x w4 weights)
        float ax = 0.0f, ay = 0.0f, az = 0.0f, aw = 0.0f;
        #pragma unroll
        for (int q = 0; q < 16; q++) {
            const float h = hw[q];
            const float4 a = w4[q];
            ax += h * a.x; ay += h * a.y; az += h * a.z; aw += h * a.w;
        }
        {
            float4 accv; accv.x = ax; accv.y = ay; accv.z = az; accv.w = aw;
            *(float4*)&ps[t & 1][s][g * 4] = accv;
        }

        __syncthreads();            // the ONLY barrier per step: ps[t&1] ready
        const int dead = sdead;

        // C: reduce + tanh + publish (publish FIRST — it's the critical path)
        if (tid < 128) {
            float z = zpre;
            #pragma unroll
            for (int q = 0; q < 32; q++) z += ps[t & 1][q][tid];
            const float hn = tanhf(z);
            if (t < Tt - 1) {
                const unsigned long long pkt =
                    ((unsigned long long)(unsigned)(t + 1) << 32) | __float_as_uint(hn);
                __hip_atomic_store(&hrow[(size_t)(t & 1) * Hh + c * 128 + tid], pkt,
                                   __ATOMIC_RELAXED, __HIP_MEMORY_SCOPE_AGENT);
            }
            rowbase[(size_t)t * Hh + c * 128 + tid] = hn;   // output (write-only)
        }

        // D: pull own k-slice window of h_t into registers (no barrier after)
        if (t < Tt - 1) {
            float f = 0.0f;
            if (g < 16 && !dead) {
                unsigned long long* src = &hrow[(size_t)(t & 1) * Hh + s * 16 + g];
                const unsigned want = (unsigned)(t + 1);
                unsigned long long v;
                int spins = 0;
                for (;;) {
                    v = __hip_atomic_load(src, __ATOMIC_RELAXED, __HIP_MEMORY_SCOPE_AGENT);
                    if ((unsigned)(v >> 32) == want) break;
                    __builtin_amdgcn_s_sleep(1);
                    if (++spins > (1 << 14)) { sdead = 1; break; }   // dead-man
                }
                f = __uint_as_float((unsigned)v);
            }
            const int base = tid & 32;    // half-wave loader base
            #pragma unroll
            for (int i = 0; i < 16; i++) hw[i] = __shfl(f, base + i, 64);
        }
    }
}

// ---------------------------------------------------------------------------
extern "C" void kernel_launch(void* const* d_in, const int* in_sizes, int n_in,
                              void* d_out, int out_size, void* d_ws, size_t ws_size,
                              hipStream_t stream) {
    const float* x = (const float*)d_in[0];    // (B, T, D)
    const float* W = (const float*)d_in[1];    // (D+H, H)
    const float* b = (const float*)d_in[2];    // (H,)
    float* out = (float*)d_out;                // (B, T, H)
    (void)d_ws; (void)ws_size;

    dim3 ggrid((Bb * Tt) / TM, Hh / TN);       // 512 x 4
    gemm_xw<<<ggrid, dim3(256), 0, stream>>>(x, W, b, out);
    scan_rnn<<<dim3(256), dim3(1024), 0, stream>>>(W, out);
}

// Round 4
// 2375.622 us; speedup vs baseline: 1.0521x; 1.0521x over previous
//
#include <hip/hip_runtime.h>
#include <math.h>

// Problem constants
#define Bb 64
#define Tt 1024
#define Dd 512
#define Hh 512

// ---------------------------------------------------------------------------
// Kernel 1: xw = x @ W[:D] + b   (M=65536, K=512, N=512), fp32.
// Unchanged (~470 us). Writes into d_out; scan overwrites in place.
// ---------------------------------------------------------------------------
#define TM 128
#define TN 128
#define TK 16
#define LDP (TN + 4)

__global__ __launch_bounds__(256) void gemm_xw(const float* __restrict__ x,
                                               const float* __restrict__ W,
                                               const float* __restrict__ bias,
                                               float* __restrict__ out) {
    __shared__ float As[TK][LDP];
    __shared__ float Bs[TK][LDP];

    const int tid = threadIdx.x;
    const int m0 = blockIdx.x * TM;
    const int n0 = blockIdx.y * TN;
    const int tx = tid & 15;
    const int ty = tid >> 4;

    float acc[8][8];
    #pragma unroll
    for (int i = 0; i < 8; i++)
        #pragma unroll
        for (int j = 0; j < 8; j++) acc[i][j] = 0.0f;

    for (int k0 = 0; k0 < Dd; k0 += TK) {
        #pragma unroll
        for (int i = 0; i < 2; i++) {
            const int idx = tid * 2 + i;
            const int r = idx >> 2;
            const int c = idx & 3;
            const float4 av = *(const float4*)(x + (size_t)(m0 + r) * Dd + k0 + c * 4);
            As[c * 4 + 0][r] = av.x;
            As[c * 4 + 1][r] = av.y;
            As[c * 4 + 2][r] = av.z;
            As[c * 4 + 3][r] = av.w;
            const int kk = idx >> 5;
            const int cg = (idx & 31) * 4;
            const float4 bv = *(const float4*)(W + (size_t)(k0 + kk) * Hh + n0 + cg);
            *(float4*)(&Bs[kk][cg]) = bv;
        }
        __syncthreads();

        #pragma unroll
        for (int kk = 0; kk < TK; kk++) {
            float a[8], b[8];
            #pragma unroll
            for (int i = 0; i < 8; i++) a[i] = As[kk][ty * 8 + i];
            #pragma unroll
            for (int j = 0; j < 8; j++) b[j] = Bs[kk][tx * 8 + j];
            #pragma unroll
            for (int i = 0; i < 8; i++)
                #pragma unroll
                for (int j = 0; j < 8; j++) acc[i][j] += a[i] * b[j];
        }
        __syncthreads();
    }

    #pragma unroll
    for (int i = 0; i < 8; i++) {
        const size_t row = (size_t)(m0 + ty * 8 + i) * Hh;
        const int n = n0 + tx * 8;
        float4 v0, v1;
        v0.x = acc[i][0] + bias[n + 0];
        v0.y = acc[i][1] + bias[n + 1];
        v0.z = acc[i][2] + bias[n + 2];
        v0.w = acc[i][3] + bias[n + 3];
        v1.x = acc[i][4] + bias[n + 4];
        v1.y = acc[i][5] + bias[n + 5];
        v1.z = acc[i][6] + bias[n + 6];
        v1.w = acc[i][7] + bias[n + 7];
        *(float4*)(out + row + n) = v0;
        *(float4*)(out + row + n + 4) = v1;
    }
}

// ---------------------------------------------------------------------------
// Kernel 2: scan, TWO ROWS PER BLOCK, software-pipelined exchange.
//
// R4 post-mortem: R3 (2 bars, LDS-h) and R4 (1 bar, reg-h) both pinned at
// ~2.0 us/step -> the IC exchange round-trip (~1.4-1.5 us: publish ->
// visible -> poll-detect) dominates and structure around it is irrelevant.
// The recurrence makes per-row latency irreducible, but rows are
// independent: interleave TWO rows per block so each row's exchange flies
// while the other row computes.
//
// Per iteration t (4 barriers), block = (c, p) handles rows p and p+32:
//   FMA_A   (all 1024 thr, reads hsA = h^A_{t-1})
//   bar1
//   {tid<128: A-fin: reduce psA + zA -> tanh -> publish tag t+1 -> outA}
//   {tid>=640, t>=1: DEFERRED pollB: want tag t -> hsB remote}  (parallel)
//   bar1.5
//   FMA_B   (all, reads hsB = h^B_{t-1})
//   bar2
//   {tid in [128,256): B-fin -> publish tag t+1 -> outB}
//   {tid in [256,640), t<Tt-1: pollA: want tag t+1 -> hsA remote} (parallel)
//   bar3
// pollA's target was published ~1300cy earlier (detects on first load);
// pollB's target gets FMA_A + bar1 of the NEXT iteration in flight before
// anyone waits. Exposed exchange latency ~ 0 if L < ~1800cy.
//
// Protocol per row unchanged (self-tagged u64, RELAXED agent atomics,
// parity slots): producer writes tag t+3 to a slot only after its poll
// consumed partners' t+2, which proves partners consumed its t+1 (skew <=
// 1 iteration; deadlock-free). Cross-replay safe without reset: stale tags
// from a previous replay never equal the strictly-increasing wants.
// Hot-spin 64 iters then s_sleep backoff; dead-man at 2^16 -> sdead
// free-runs (wrong answer + counters, never a dead container).
//
// 128 blocks (all trivially co-resident on 256 CUs). bid = c*32 + p keeps
// a row's 4 partner blocks on one XCD under round-robin (heuristic only).
// Weights fp32 in regs/AGPRs (keep-alive); ~60 VGPR + 64 AGPR < 128 cap.
// LDS: 2x16KB ps + 2x2KB hs = 36 KB.
// ---------------------------------------------------------------------------
__device__ unsigned long long g_hbuf[(size_t)Bb * 2 * Hh];   // 512 KB .bss

__global__ __launch_bounds__(1024, 4) void scan_rnn(const float* __restrict__ W,
                                                    float* __restrict__ out) {
    const float* __restrict__ Wh = W + (size_t)Dd * Hh;   // (H, H) row-major
    const int p = blockIdx.x & 31;        // row-pair index: rows p, p+32
    const int c = blockIdx.x >> 5;        // column group, 0..3
    const int tid = threadIdx.x;
    const int g = tid & 31;               // 4-col group within slice
    const int s = tid >> 5;               // k-slice, 0..31

    float* baseA = out + (size_t)p * Tt * Hh + (size_t)c * 128;
    float* baseB = out + (size_t)(p + 32) * Tt * Hh + (size_t)c * 128;
    unsigned long long* hrowA = g_hbuf + (size_t)p * 2 * Hh;         // [2][512]
    unsigned long long* hrowB = g_hbuf + (size_t)(p + 32) * 2 * Hh;

    __shared__ float hsA[Hh], hsB[Hh];
    __shared__ float psA[32][128], psB[32][128];
    __shared__ int sdead;

    // ---- weight slice in registers: w4[kk] = Wh[16s+kk][128c+4g .. +3]
    float4 w4[16];
    {
        const float4* wbase = (const float4*)(Wh + (size_t)(s * 16) * Hh) + (c * 32 + g);
        #pragma unroll
        for (int kk = 0; kk < 16; kk++) w4[kk] = wbase[(size_t)kk * 128];
    }
    #pragma unroll
    for (int kk = 0; kk < 16; kk++)
        asm volatile("" : "+v"(w4[kk].x), "+v"(w4[kk].y), "+v"(w4[kk].z), "+v"(w4[kk].w));

    if (tid < Hh) { hsA[tid] = 0.0f; hsB[tid] = 0.0f; }
    if (tid == 0) sdead = 0;
    __syncthreads();

    for (int t = 0; t < Tt; t++) {
        // prefetch xw for this step (in flight through FMA phases)
        float zA = 0.0f, zB = 0.0f;
        if (tid < 128)      zA = baseA[(size_t)t * Hh + tid];
        else if (tid < 256) zB = baseB[(size_t)t * Hh + (tid - 128)];

        // ---- FMA A: psA = Wh-slice . h^A_{t-1}
        {
            float ax = 0.f, ay = 0.f, az = 0.f, aw = 0.f;
            #pragma unroll
            for (int kq = 0; kq < 4; kq++) {
                const float4 hv = *(const float4*)&hsA[s * 16 + kq * 4];
                const float4 a0 = w4[kq * 4 + 0];
                const float4 a1 = w4[kq * 4 + 1];
                const float4 a2 = w4[kq * 4 + 2];
                const float4 a3 = w4[kq * 4 + 3];
                ax += hv.x * a0.x; ay += hv.x * a0.y; az += hv.x * a0.z; aw += hv.x * a0.w;
                ax += hv.y * a1.x; ay += hv.y * a1.y; az += hv.y * a1.z; aw += hv.y * a1.w;
                ax += hv.z * a2.x; ay += hv.z * a2.y; az += hv.z * a2.z; aw += hv.z * a2.w;
                ax += hv.w * a3.x; ay += hv.w * a3.y; az += hv.w * a3.z; aw += hv.w * a3.w;
            }
            float4 v; v.x = ax; v.y = ay; v.z = az; v.w = aw;
            *(float4*)&psA[s][g * 4] = v;
        }
        __syncthreads();                               // bar1: psA ready

        // ---- A finalize (waves 0-1)  ||  deferred pollB (waves 10-15)
        if (tid < 128) {
            float z = zA;
            #pragma unroll
            for (int q = 0; q < 32; q++) z += psA[q][tid];
            const float hn = tanhf(z);
            if (t < Tt - 1) {
                const unsigned long long pkt =
                    ((unsigned long long)(unsigned)(t + 1) << 32) | __float_as_uint(hn);
                __hip_atomic_store(&hrowA[(size_t)(t & 1) * Hh + c * 128 + tid], pkt,
                                   __ATOMIC_RELAXED, __HIP_MEMORY_SCOPE_AGENT);
                hsA[c * 128 + tid] = hn;
            }
            baseA[(size_t)t * Hh + tid] = hn;
        } else if (tid >= 640 && t >= 1 && sdead == 0) {
            // pollB: want tag t == h^B_{t-1} remote, slot (t-1)&1
            const int idx = tid - 640;
            const int pp = idx >> 7;
            const int cp = pp + (pp >= c ? 1 : 0);
            const int jj = idx & 127;
            unsigned long long* src = &hrowB[(size_t)((t - 1) & 1) * Hh + cp * 128 + jj];
            const unsigned want = (unsigned)t;
            unsigned long long v;
            int spins = 0;
            for (;;) {
                v = __hip_atomic_load(src, __ATOMIC_RELAXED, __HIP_MEMORY_SCOPE_AGENT);
                if ((unsigned)(v >> 32) == want) break;
                if (++spins > 64) __builtin_amdgcn_s_sleep(1);
                if (spins > (1 << 16)) { sdead = 1; break; }
            }
            hsB[cp * 128 + jj] = __uint_as_float((unsigned)v);
        }
        __syncthreads();                               // bar1.5: hsB complete

        // ---- FMA B: psB = Wh-slice . h^B_{t-1}
        {
            float ax = 0.f, ay = 0.f, az = 0.f, aw = 0.f;
            #pragma unroll
            for (int kq = 0; kq < 4; kq++) {
                const float4 hv = *(const float4*)&hsB[s * 16 + kq * 4];
                const float4 a0 = w4[kq * 4 + 0];
                const float4 a1 = w4[kq * 4 + 1];
                const float4 a2 = w4[kq * 4 + 2];
                const float4 a3 = w4[kq * 4 + 3];
                ax += hv.x * a0.x; ay += hv.x * a0.y; az += hv.x * a0.z; aw += hv.x * a0.w;
                ax += hv.y * a1.x; ay += hv.y * a1.y; az += hv.y * a1.z; aw += hv.y * a1.w;
                ax += hv.z * a2.x; ay += hv.z * a2.y; az += hv.z * a2.z; aw += hv.z * a2.w;
                ax += hv.w * a3.x; ay += hv.w * a3.y; az += hv.w * a3.z; aw += hv.w * a3.w;
            }
            float4 v; v.x = ax; v.y = ay; v.z = az; v.w = aw;
            *(float4*)&psB[s][g * 4] = v;
        }
        __syncthreads();                               // bar2: psB ready

        // ---- B finalize (waves 2-3)  ||  pollA (waves 4-9)
        if (tid >= 128 && tid < 256) {
            const int j = tid - 128;
            float z = zB;
            #pragma unroll
            for (int q = 0; q < 32; q++) z += psB[q][j];
            const float hn = tanhf(z);
            if (t < Tt - 1) {
                const unsigned long long pkt =
                    ((unsigned long long)(unsigned)(t + 1) << 32) | __float_as_uint(hn);
                __hip_atomic_store(&hrowB[(size_t)(t & 1) * Hh + c * 128 + j], pkt,
                                   __ATOMIC_RELAXED, __HIP_MEMORY_SCOPE_AGENT);
                hsB[c * 128 + j] = hn;
            }
            baseB[(size_t)t * Hh + j] = hn;
        } else if (tid >= 256 && tid < 640 && t < Tt - 1 && sdead == 0) {
            // pollA: want tag t+1 == h^A_t remote, slot t&1 (published ~1300cy ago)
            const int idx = tid - 256;
            const int pp = idx >> 7;
            const int cp = pp + (pp >= c ? 1 : 0);
            const int jj = idx & 127;
            unsigned long long* src = &hrowA[(size_t)(t & 1) * Hh + cp * 128 + jj];
            const unsigned want = (unsigned)(t + 1);
            unsigned long long v;
            int spins = 0;
            for (;;) {
                v = __hip_atomic_load(src, __ATOMIC_RELAXED, __HIP_MEMORY_SCOPE_AGENT);
                if ((unsigned)(v >> 32) == want) break;
                if (++spins > 64) __builtin_amdgcn_s_sleep(1);
                if (spins > (1 << 16)) { sdead = 1; break; }
            }
            hsA[cp * 128 + jj] = __uint_as_float((unsigned)v);
        }
        __syncthreads();                               // bar3: hsA complete
    }
}

// ---------------------------------------------------------------------------
extern "C" void kernel_launch(void* const* d_in, const int* in_sizes, int n_in,
                              void* d_out, int out_size, void* d_ws, size_t ws_size,
                              hipStream_t stream) {
    const float* x = (const float*)d_in[0];    // (B, T, D)
    const float* W = (const float*)d_in[1];    // (D+H, H)
    const float* b = (const float*)d_in[2];    // (H,)
    float* out = (float*)d_out;                // (B, T, H)
    (void)d_ws; (void)ws_size;

    dim3 ggrid((Bb * Tt) / TM, Hh / TN);       // 512 x 4
    gemm_xw<<<ggrid, dim3(256), 0, stream>>>(x, W, b, out);
    scan_rnn<<<dim3(128), dim3(1024), 0, stream>>>(W, out);
}